// Round 4
// baseline (182.074 us; speedup 1.0000x reference)
//
#include <hip/hip_runtime.h>
#include <math.h>

// Shapes: S=4 B=8 N=2048 K=16 D=32 H=128; SBN=65536 rows; 2048 rows/sb.
typedef float v2f __attribute__((ext_vector_type(2)));

#define EXP2F(x) __builtin_amdgcn_exp2f(x)
#define RCPF(x)  __builtin_amdgcn_rcpf(x)
#define C_SCALE 2.8853900817779268f   // 2*log2(e): tanh(z)=1-2/(1+2^(c*z))
#define L2E 1.4426950408889634f

#if __has_builtin(__builtin_elementwise_fma)
static __device__ __forceinline__ v2f fma2(v2f a, v2f b, v2f c) {
  return __builtin_elementwise_fma(a, b, c);
}
#else
static __device__ __forceinline__ v2f fma2(v2f a, v2f b, v2f c) {
  v2f r; r.x = fmaf(a.x, b.x, c.x); r.y = fmaf(a.y, b.y, c.y); return r;
}
#endif

// ---------------------------------------------------------------------------
// prep:
//   ekT[sb*2048 + h*16 + k] = exp2(c*(mu[sb,k]@Wm[:,h] + tau[sb,k]@Wt[:,h] + b1[h]))
//   WTc[h*32 + d]           = c * Wx[d,h]      (transposed, pre-scaled)
//   w2n[h]                  = -2 * W2[h]
// ---------------------------------------------------------------------------
__global__ __launch_bounds__(256) void prep_kernel(
    const float* __restrict__ mu, const float* __restrict__ tau,
    const float* __restrict__ W1, const float* __restrict__ b1,
    const float* __restrict__ W2,
    float* __restrict__ ekT, float* __restrict__ WTc, float* __restrict__ w2n) {
  int g = blockIdx.x * 256 + threadIdx.x;    // 0..65535
  int h = g & 127, row = g >> 7;             // row = sb*16+k (512 rows)
  const float* mur  = mu  + row * 32;
  const float* taur = tau + row * 32;
  float acc = b1[h];
#pragma unroll
  for (int d = 0; d < 32; ++d) {
    acc = fmaf(mur[d],  W1[(32 + d) * 128 + h], acc);   // Wm
    acc = fmaf(taur[d], W1[(64 + d) * 128 + h], acc);   // Wt
  }
  int sb = row >> 4, k = row & 15;
  ekT[sb * 2048 + h * 16 + k] = EXP2F(C_SCALE * acc);
  if (g < 4096) {                           // WTc[h'*32+d] = c*W1[d*128+h']
    int hh = g >> 5, d = g & 31;
    WTc[g] = C_SCALE * W1[d * 128 + hh];
  }
  if (g < 128) w2n[g] = -2.0f * W2[g];
}

// ---------------------------------------------------------------------------
// main: NO LDS. Thread = 2 rows x 32-h slice x all 16 k.
//   x rows in VGPRs (global loads); W/ekT/w2n wave-uniform -> s_load/SGPR.
//   per h: ex[r]=exp2(x@WTc[h]); acc[r][k] += w2n[h]*rcp(1+ex[r]*ekT[h][k])
//   hg in {0..3} slices h; partials reduced via shfl_xor(1,2); softmax in-reg.
// ---------------------------------------------------------------------------
__global__ __launch_bounds__(256, 4) void main_kernel(
    const float* __restrict__ x, const float* __restrict__ WTc,
    const float* __restrict__ ekT, const float* __restrict__ w2n,
    float* __restrict__ out) {
  int t = threadIdx.x;
  int hg = t & 3, rp = t >> 2;               // 4 h-groups x 64 row-pairs
  int row0 = blockIdx.x * 128;               // 128 rows per block
  int sb = row0 >> 11;
  int r0 = row0 + rp * 2;

  // private x rows -> VGPRs (hg-duplicated reads; L1 absorbs)
  v2f xr[2][16];
#pragma unroll
  for (int rr = 0; rr < 2; ++rr) {
    const float4* xp = (const float4*)(x + (size_t)(r0 + rr) * 32);
#pragma unroll
    for (int i = 0; i < 8; ++i) {
      float4 v = xp[i];
      xr[rr][2 * i]     = (v2f){v.x, v.y};
      xr[rr][2 * i + 1] = (v2f){v.z, v.w};
    }
  }

  const v2f* Wp  = (const v2f*)WTc;                        // [128][16] v2f
  const v2f* ekp = (const v2f*)(ekT + (size_t)sb * 2048);  // [128][8]  v2f

  v2f acc[2][8];
#pragma unroll
  for (int rr = 0; rr < 2; ++rr)
#pragma unroll
    for (int j = 0; j < 8; ++j) acc[rr][j] = (v2f){0.f, 0.f};

  int h0 = hg * 32;
#pragma unroll 1
  for (int hh = 0; hh < 32; ++hh) {
    int h = h0 + hh;
    // wave-uniform scalar fetches (SGPR)
    v2f w[16];
    const v2f* wrow = Wp + h * 16;
#pragma unroll
    for (int i = 0; i < 16; ++i) w[i] = wrow[i];
    v2f ek2[8];
    const v2f* ekh = ekp + h * 8;
#pragma unroll
    for (int j = 0; j < 8; ++j) ek2[j] = ekh[j];
    float w2 = w2n[h];

    // GEMM slice: ex[r] = exp2(dot32)
    float ex[2];
#pragma unroll
    for (int rr = 0; rr < 2; ++rr) {
      v2f p = (v2f){0.f, 0.f};
#pragma unroll
      for (int i = 0; i < 16; ++i) p = fma2(xr[rr][i], w[i], p);
      ex[rr] = EXP2F(p.x + p.y);
    }
    // sigma + accumulate: fma(v,s,1) -> rcp -> fma(s,v,acc)
#pragma unroll
    for (int rr = 0; rr < 2; ++rr) {
      v2f exd = (v2f){ex[rr], ex[rr]};
#pragma unroll
      for (int j = 0; j < 8; ++j) {
        v2f tt = fma2(exd, ek2[j], (v2f){1.f, 1.f});
        v2f rv = (v2f){RCPF(tt.x), RCPF(tt.y)};
        acc[rr][j] = fma2((v2f){w2, w2}, rv, acc[rr][j]);
      }
    }
  }

  // reduce the 4 h-slice partials: lanes 4*rp+hg, xor over bits 0..1
#pragma unroll
  for (int m = 1; m <= 2; m <<= 1) {
#pragma unroll
    for (int rr = 0; rr < 2; ++rr)
#pragma unroll
      for (int j = 0; j < 8; ++j) {
        acc[rr][j].x += __shfl_xor(acc[rr][j].x, m);
        acc[rr][j].y += __shfl_xor(acc[rr][j].y, m);
      }
  }

  // softmax over 16 k (all in-register; all hg lanes identical), store k-quad
#pragma unroll
  for (int rr = 0; rr < 2; ++rr) {
    float g[16];
#pragma unroll
    for (int j = 0; j < 8; ++j) { g[2 * j] = acc[rr][j].x; g[2 * j + 1] = acc[rr][j].y; }
    float mx = g[0];
#pragma unroll
    for (int k = 1; k < 16; ++k) mx = fmaxf(mx, g[k]);
    float p[16], sum = 0.f;
#pragma unroll
    for (int k = 0; k < 16; ++k) { p[k] = EXP2F((g[k] - mx) * L2E); sum += p[k]; }
    float inv = RCPF(sum);
    float4 o = {p[hg * 4] * inv, p[hg * 4 + 1] * inv,
                p[hg * 4 + 2] * inv, p[hg * 4 + 3] * inv};
    *(float4*)&out[(size_t)(r0 + rr) * 16 + hg * 4] = o;
  }
}

// ---------------------------------------------------------------------------
extern "C" void kernel_launch(void* const* d_in, const int* in_sizes, int n_in,
                              void* d_out, int out_size, void* d_ws, size_t ws_size,
                              hipStream_t stream) {
  const float* x   = (const float*)d_in[0];
  const float* mu  = (const float*)d_in[1];
  const float* tau = (const float*)d_in[2];
  const float* W1  = (const float*)d_in[3];
  const float* b1  = (const float*)d_in[4];
  const float* W2  = (const float*)d_in[5];
  // b2 (d_in[6]) and sum(W2) are k-uniform -> cancelled by softmax.
  float* out = (float*)d_out;

  float* ekT = (float*)d_ws;              // 32*2048 f32 = 256 KB
  float* WTc = ekT + 32 * 2048;           // 4096 f32 = 16 KB
  float* w2n = WTc + 4096;                // 128 f32
  (void)in_sizes; (void)n_in; (void)out_size; (void)ws_size;

  prep_kernel<<<256, 256, 0, stream>>>(mu, tau, W1, b1, W2, ekT, WTc, w2n);
  main_kernel<<<512, 256, 0, stream>>>(x, WTc, ekT, w2n, out);
}

// Round 5
// 100.398 us; speedup vs baseline: 1.8135x; 1.8135x over previous
//
#include <hip/hip_runtime.h>
#include <math.h>

// Shapes: S=4 B=8 N=2048 K=16 D=32 H=128; SBN=65536 rows; 2048 rows/sb.
#define EXP2F(x) __builtin_amdgcn_exp2f(x)
#define RCPF(x)  __builtin_amdgcn_rcpf(x)
#define C_SCALE 2.8853900817779268f   // 2*log2(e): tanh(z)=1-2/(1+2^(c*z))
#define L2E 1.4426950408889634f

// ---------------------------------------------------------------------------
// prep (write-coalesced):
//   ekT[sb*2048 + h*16 + k] = exp2(c*(mu[sb,k]@Wm[:,h] + tau[sb,k]@Wt[:,h] + b1[h]))
//   WTc[h*32 + d]           = c * Wx[d,h]
//   w2n[h]                  = -2 * W2[h]
// ---------------------------------------------------------------------------
__global__ __launch_bounds__(256) void prep_kernel(
    const float* __restrict__ mu, const float* __restrict__ tau,
    const float* __restrict__ W1, const float* __restrict__ b1,
    const float* __restrict__ W2,
    float* __restrict__ ekT, float* __restrict__ WTc, float* __restrict__ w2n) {
  int g = blockIdx.x * 256 + threadIdx.x;    // 0..65535 == sb*2048 + h*16 + k
  int k = g & 15, h = (g >> 4) & 127, sb = g >> 11;
  int row = sb * 16 + k;
  const float* mur  = mu  + row * 32;
  const float* taur = tau + row * 32;
  float acc = b1[h];
#pragma unroll
  for (int d = 0; d < 32; ++d) {
    acc = fmaf(mur[d],  W1[(32 + d) * 128 + h], acc);   // Wm
    acc = fmaf(taur[d], W1[(64 + d) * 128 + h], acc);   // Wt
  }
  ekT[g] = EXP2F(C_SCALE * acc);
  if (g < 4096) {                           // WTc[h'*32+d] = c*W1[d*128+h']
    int hh = g >> 5, d = g & 31;
    WTc[g] = C_SCALE * W1[d * 128 + hh];
  }
  if (g < 128) w2n[g] = -2.0f * W2[g];
}

// ---------------------------------------------------------------------------
// main: hot loop has ZERO LDS and ZERO vector-memory traffic.
//   Block = 256 thr = 4 waves; wave wv owns h-slice [wv*32, wv*32+32);
//   lane = 1 row (64 rows/block). W/ek/w2 addresses are WAVE-UNIFORM ->
//   s_load -> SGPR operands folded straight into v_fma.
//   Per h: ex = exp2(x@Wc[:,h]);  acc[k] += w2[h] * rcp(1 + ex*ekT[h][k])
//   Cross-wave reduce via LDS once; 4-lane shuffle softmax; float4 stores.
// ---------------------------------------------------------------------------
__global__ __launch_bounds__(256, 4) void main_kernel(
    const float* __restrict__ x, const float* __restrict__ WTc,
    const float* __restrict__ ekT, const float* __restrict__ w2n,
    float* __restrict__ out) {
  __shared__ float pSum[4][64][17];          // stride 17: conflict-free b32
  int t = threadIdx.x;
  int lane = t & 63;
  int wv = __builtin_amdgcn_readfirstlane(t >> 6);   // wave id: 0..3
  int row0 = blockIdx.x * 64;
  int sb = row0 >> 11;
  int r = row0 + lane;

  // ---- private x row -> VGPRs (8 x dwordx4) ----
  float xr[32];
  {
    const float4* xp = (const float4*)(x + (size_t)r * 32);
#pragma unroll
    for (int i = 0; i < 8; ++i) {
      float4 v = xp[i];
      xr[4 * i] = v.x; xr[4 * i + 1] = v.y; xr[4 * i + 2] = v.z; xr[4 * i + 3] = v.w;
    }
  }

  // wave-uniform bases
  const float* Wb  = WTc + wv * 32 * 32;                  // 32 h-rows x 32 d
  const float* ekb = ekT + (size_t)sb * 2048 + wv * 32 * 16;
  const float* w2b = w2n + wv * 32;

  float acc[16];
#pragma unroll
  for (int k = 0; k < 16; ++k) acc[k] = 0.f;

#pragma unroll 2
  for (int hh = 0; hh < 32; ++hh) {
    const float* wr = Wb + hh * 32;          // uniform -> s_load
    float d0 = 0.f, d1 = 0.f, d2 = 0.f, d3 = 0.f;
#pragma unroll
    for (int i = 0; i < 8; ++i) {
      d0 = fmaf(xr[4 * i],     wr[4 * i],     d0);
      d1 = fmaf(xr[4 * i + 1], wr[4 * i + 1], d1);
      d2 = fmaf(xr[4 * i + 2], wr[4 * i + 2], d2);
      d3 = fmaf(xr[4 * i + 3], wr[4 * i + 3], d3);
    }
    float ex = EXP2F((d0 + d1) + (d2 + d3));
    const float* ekr = ekb + hh * 16;        // uniform -> s_load (64 B)
    float w2 = w2b[hh];                      // uniform -> SGPR
#pragma unroll
    for (int k = 0; k < 16; ++k) {
      float tt = fmaf(ex, ekr[k], 1.0f);     // v_fma with SGPR operand
      acc[k] = fmaf(w2, RCPF(tt), acc[k]);   // v_rcp + v_fma(SGPR)
    }
  }

  // ---- cross-wave reduction (once) ----
#pragma unroll
  for (int k = 0; k < 16; ++k) pSum[wv][lane][k] = acc[k];
  __syncthreads();

  // thread t: row rr = t>>2 (0..63), k-quad q = t&3
  int rr = t >> 2, q = t & 3;
  float g0, g1, g2, g3;
  {
    int kb = q * 4;
    g0 = pSum[0][rr][kb]     + pSum[1][rr][kb]     + pSum[2][rr][kb]     + pSum[3][rr][kb];
    g1 = pSum[0][rr][kb + 1] + pSum[1][rr][kb + 1] + pSum[2][rr][kb + 1] + pSum[3][rr][kb + 1];
    g2 = pSum[0][rr][kb + 2] + pSum[1][rr][kb + 2] + pSum[2][rr][kb + 2] + pSum[3][rr][kb + 2];
    g3 = pSum[0][rr][kb + 3] + pSum[1][rr][kb + 3] + pSum[2][rr][kb + 3] + pSum[3][rr][kb + 3];
  }
  // softmax over 16 k = 4 in-thread x 4 lanes (shuffle width 4)
  float mx = fmaxf(fmaxf(g0, g1), fmaxf(g2, g3));
#pragma unroll
  for (int m = 1; m <= 2; m <<= 1) mx = fmaxf(mx, __shfl_xor(mx, m, 4));
  float p0 = EXP2F((g0 - mx) * L2E), p1 = EXP2F((g1 - mx) * L2E);
  float p2 = EXP2F((g2 - mx) * L2E), p3 = EXP2F((g3 - mx) * L2E);
  float sum = (p0 + p1) + (p2 + p3);
#pragma unroll
  for (int m = 1; m <= 2; m <<= 1) sum += __shfl_xor(sum, m, 4);
  float inv = RCPF(sum);
  float4 o = {p0 * inv, p1 * inv, p2 * inv, p3 * inv};
  *(float4*)&out[(size_t)(row0 + rr) * 16 + q * 4] = o;
}

// ---------------------------------------------------------------------------
extern "C" void kernel_launch(void* const* d_in, const int* in_sizes, int n_in,
                              void* d_out, int out_size, void* d_ws, size_t ws_size,
                              hipStream_t stream) {
  const float* x   = (const float*)d_in[0];
  const float* mu  = (const float*)d_in[1];
  const float* tau = (const float*)d_in[2];
  const float* W1  = (const float*)d_in[3];
  const float* b1  = (const float*)d_in[4];
  const float* W2  = (const float*)d_in[5];
  // b2 (d_in[6]) and sum(W2) are k-uniform -> cancelled by softmax.
  float* out = (float*)d_out;

  float* ekT = (float*)d_ws;              // 32*2048 f32 = 256 KB
  float* WTc = ekT + 32 * 2048;           // 4096 f32 = 16 KB
  float* w2n = WTc + 4096;                // 128 f32
  (void)in_sizes; (void)n_in; (void)out_size; (void)ws_size;

  prep_kernel<<<256, 256, 0, stream>>>(mu, tau, W1, b1, W2, ekT, WTc, w2n);
  main_kernel<<<1024, 256, 0, stream>>>(x, WTc, ekT, w2n, out);
}

// Round 6
// 100.109 us; speedup vs baseline: 1.8188x; 1.0029x over previous
//
#include <hip/hip_runtime.h>
#include <math.h>

// Shapes: S=4 B=8 N=2048 K=16 D=32 H=128; SBN=65536 rows; 2048 rows/sb.
#define EXP2F(x) __builtin_amdgcn_exp2f(x)
#define RCPF(x)  __builtin_amdgcn_rcpf(x)
#define C_SCALE 2.8853900817779268f   // 2*log2(e): tanh(z)=1-2/(1+2^(c*z))
#define L2E 1.4426950408889634f

// Constant-address-space alias: loads through this are guaranteed SMEM
// (s_load) when the address is wave-uniform — no noclobber analysis needed.
typedef __attribute__((address_space(4))) const float c4f;
static __device__ __forceinline__ c4f* as_const(const float* p) {
  return (c4f*)(unsigned long long)p;
}

// ---------------------------------------------------------------------------
// prep (write-coalesced):
//   ekT[sb*2048 + h*16 + k] = exp2(c*(mu[sb,k]@Wm[:,h] + tau[sb,k]@Wt[:,h] + b1[h]))
//   WTc[h*32 + d]           = c * Wx[d,h]
//   w2n[h]                  = -2 * W2[h]
// ---------------------------------------------------------------------------
__global__ __launch_bounds__(256) void prep_kernel(
    const float* __restrict__ mu, const float* __restrict__ tau,
    const float* __restrict__ W1, const float* __restrict__ b1,
    const float* __restrict__ W2,
    float* __restrict__ ekT, float* __restrict__ WTc, float* __restrict__ w2n) {
  int g = blockIdx.x * 256 + threadIdx.x;    // 0..65535 == sb*2048 + h*16 + k
  int k = g & 15, h = (g >> 4) & 127, sb = g >> 11;
  int row = sb * 16 + k;
  const float* mur  = mu  + row * 32;
  const float* taur = tau + row * 32;
  float acc = b1[h];
#pragma unroll
  for (int d = 0; d < 32; ++d) {
    acc = fmaf(mur[d],  W1[(32 + d) * 128 + h], acc);   // Wm
    acc = fmaf(taur[d], W1[(64 + d) * 128 + h], acc);   // Wt
  }
  ekT[g] = EXP2F(C_SCALE * acc);
  if (g < 4096) {                           // WTc[h'*32+d] = c*W1[d*128+h']
    int hh = g >> 5, d = g & 31;
    WTc[g] = C_SCALE * W1[d * 128 + hh];
  }
  if (g < 128) w2n[g] = -2.0f * W2[g];
}

// ---------------------------------------------------------------------------
// main: hot loop = SMEM (scalar) loads + VALU/trans only. No LDS, no VMEM.
//   Block = 4 waves; wave wv owns h-slice [wv*32, wv*32+32); lane = 1 row.
//   Per h: ex = exp2(x@Wc[:,h]);  acc[k] += w2[h] * rcp(1 + ex*ekT[h][k])
//   (v_fma takes exactly one SGPR operand per instr -> all legal.)
//   Cross-wave reduce via LDS once; 4-lane shuffle softmax; float4 stores.
// ---------------------------------------------------------------------------
__global__ __launch_bounds__(256, 4) void main_kernel(
    const float* __restrict__ x, const float* __restrict__ WTc,
    const float* __restrict__ ekT, const float* __restrict__ w2n,
    float* __restrict__ out) {
  __shared__ float pSum[4][64][17];          // 17.4 KB; stride 17 conflict-free
  int t = threadIdx.x;
  int lane = t & 63;
  int wv = __builtin_amdgcn_readfirstlane(t >> 6);   // wave id: 0..3
  int row0 = blockIdx.x * 64;
  int sb = row0 >> 11;
  int r = row0 + lane;

  // ---- private x row -> VGPRs (8 x dwordx4) ----
  float xr[32];
  {
    const float4* xp = (const float4*)(x + (size_t)r * 32);
#pragma unroll
    for (int i = 0; i < 8; ++i) {
      float4 v = xp[i];
      xr[4 * i] = v.x; xr[4 * i + 1] = v.y; xr[4 * i + 2] = v.z; xr[4 * i + 3] = v.w;
    }
  }

  // wave-uniform scalar-pipe bases (constant addrspace -> s_load)
  c4f* Wb  = as_const(WTc + wv * 32 * 32);                 // 32 h-rows x 32 d
  c4f* ekb = as_const(ekT + (size_t)sb * 2048 + wv * 32 * 16);
  c4f* w2b = as_const(w2n + wv * 32);

  float acc[16];
#pragma unroll
  for (int k = 0; k < 16; ++k) acc[k] = 0.f;

#pragma unroll 1
  for (int hh = 0; hh < 32; ++hh) {
    c4f* wr = Wb + hh * 32;                  // s_load_dwordx8 x4
    float d0 = 0.f, d1 = 0.f, d2 = 0.f, d3 = 0.f;
#pragma unroll
    for (int i = 0; i < 8; ++i) {
      d0 = fmaf(xr[4 * i],     wr[4 * i],     d0);
      d1 = fmaf(xr[4 * i + 1], wr[4 * i + 1], d1);
      d2 = fmaf(xr[4 * i + 2], wr[4 * i + 2], d2);
      d3 = fmaf(xr[4 * i + 3], wr[4 * i + 3], d3);
    }
    float ex = EXP2F((d0 + d1) + (d2 + d3));
    c4f* ekr = ekb + hh * 16;                // s_load_dwordx8 x2
    float w2 = w2b[hh];                      // s_load_dword
#pragma unroll
    for (int k = 0; k < 16; ++k) {
      float tt = fmaf(ex, ekr[k], 1.0f);     // v_fma: 1 SGPR + inline const
      acc[k] = fmaf(w2, RCPF(tt), acc[k]);   // v_rcp + v_fma (1 SGPR)
    }
  }

  // ---- cross-wave reduction (once) ----
#pragma unroll
  for (int k = 0; k < 16; ++k) pSum[wv][lane][k] = acc[k];
  __syncthreads();

  // thread t: row rr = t>>2 (0..63), k-quad q = t&3
  int rr = t >> 2, q = t & 3;
  int kb = q * 4;
  float g0 = pSum[0][rr][kb]     + pSum[1][rr][kb]     + pSum[2][rr][kb]     + pSum[3][rr][kb];
  float g1 = pSum[0][rr][kb + 1] + pSum[1][rr][kb + 1] + pSum[2][rr][kb + 1] + pSum[3][rr][kb + 1];
  float g2 = pSum[0][rr][kb + 2] + pSum[1][rr][kb + 2] + pSum[2][rr][kb + 2] + pSum[3][rr][kb + 2];
  float g3 = pSum[0][rr][kb + 3] + pSum[1][rr][kb + 3] + pSum[2][rr][kb + 3] + pSum[3][rr][kb + 3];

  // softmax over 16 k = 4 in-thread x 4 lanes (shuffle width 4)
  float mx = fmaxf(fmaxf(g0, g1), fmaxf(g2, g3));
#pragma unroll
  for (int m = 1; m <= 2; m <<= 1) mx = fmaxf(mx, __shfl_xor(mx, m, 4));
  float p0 = EXP2F((g0 - mx) * L2E), p1 = EXP2F((g1 - mx) * L2E);
  float p2 = EXP2F((g2 - mx) * L2E), p3 = EXP2F((g3 - mx) * L2E);
  float sum = (p0 + p1) + (p2 + p3);
#pragma unroll
  for (int m = 1; m <= 2; m <<= 1) sum += __shfl_xor(sum, m, 4);
  float inv = RCPF(sum);
  float4 o = {p0 * inv, p1 * inv, p2 * inv, p3 * inv};
  *(float4*)&out[(size_t)(row0 + rr) * 16 + q * 4] = o;
}

// ---------------------------------------------------------------------------
extern "C" void kernel_launch(void* const* d_in, const int* in_sizes, int n_in,
                              void* d_out, int out_size, void* d_ws, size_t ws_size,
                              hipStream_t stream) {
  const float* x   = (const float*)d_in[0];
  const float* mu  = (const float*)d_in[1];
  const float* tau = (const float*)d_in[2];
  const float* W1  = (const float*)d_in[3];
  const float* b1  = (const float*)d_in[4];
  const float* W2  = (const float*)d_in[5];
  // b2 (d_in[6]) and sum(W2) are k-uniform -> cancelled by softmax.
  float* out = (float*)d_out;

  float* ekT = (float*)d_ws;              // 32*2048 f32 = 256 KB
  float* WTc = ekT + 32 * 2048;           // 4096 f32 = 16 KB
  float* w2n = WTc + 4096;                // 128 f32
  (void)in_sizes; (void)n_in; (void)out_size; (void)ws_size;

  prep_kernel<<<256, 256, 0, stream>>>(mu, tau, W1, b1, W2, ekT, WTc, w2n);
  main_kernel<<<1024, 256, 0, stream>>>(x, WTc, ekT, w2n, out);
}

// Round 7
// 95.790 us; speedup vs baseline: 1.9008x; 1.0451x over previous
//
#include <hip/hip_runtime.h>
#include <math.h>

// Shapes: S=4 B=8 N=2048 K=16 D=32 H=128; SBN=65536 rows; 2048 rows/sb.
typedef float v2f __attribute__((ext_vector_type(2)));

#define EXP2F(x) __builtin_amdgcn_exp2f(x)
#define RCPF(x)  __builtin_amdgcn_rcpf(x)
#define C_SCALE 2.8853900817779268f   // 2*log2(e): tanh(z)=1-2/(1+2^(c*z))
#define L2E 1.4426950408889634f

static __device__ __forceinline__ v2f fma2(v2f a, v2f b, v2f c) {
#if __has_builtin(__builtin_elementwise_fma)
  return __builtin_elementwise_fma(a, b, c);
#else
  v2f r; r.x = fmaf(a.x, b.x, c.x); r.y = fmaf(a.y, b.y, c.y); return r;
#endif
}

// Constant addrspace: wave-uniform loads lower to s_load (SMEM).
typedef __attribute__((address_space(4))) const float c4f;
static __device__ __forceinline__ c4f* as_const(const float* p) {
  return (c4f*)(unsigned long long)p;
}

// ---------------------------------------------------------------------------
// prep (write-coalesced):
//   ekT[sb*2048 + h*16 + k] = exp2(c*(mu[sb,k]@Wm[:,h] + tau[sb,k]@Wt[:,h] + b1[h]))
//   WTc[h*32 + d]           = c * Wx[d,h]
//   w2n[h]                  = -2 * W2[h]
// ---------------------------------------------------------------------------
__global__ __launch_bounds__(256) void prep_kernel(
    const float* __restrict__ mu, const float* __restrict__ tau,
    const float* __restrict__ W1, const float* __restrict__ b1,
    const float* __restrict__ W2,
    float* __restrict__ ekT, float* __restrict__ WTc, float* __restrict__ w2n) {
  int g = blockIdx.x * 256 + threadIdx.x;    // 0..65535 == sb*2048 + h*16 + k
  int k = g & 15, h = (g >> 4) & 127, sb = g >> 11;
  int row = sb * 16 + k;
  const float* mur  = mu  + row * 32;
  const float* taur = tau + row * 32;
  float acc = b1[h];
#pragma unroll
  for (int d = 0; d < 32; ++d) {
    acc = fmaf(mur[d],  W1[(32 + d) * 128 + h], acc);   // Wm
    acc = fmaf(taur[d], W1[(64 + d) * 128 + h], acc);   // Wt
  }
  ekT[g] = EXP2F(C_SCALE * acc);
  if (g < 4096) {                           // WTc[h'*32+d] = c*W1[d*128+h']
    int hh = g >> 5, d = g & 31;
    WTc[g] = C_SCALE * W1[d * 128 + hh];
  }
  if (g < 128) w2n[g] = -2.0f * W2[g];
}

// ---------------------------------------------------------------------------
// main: 512 thr = 8 waves; wave wv owns 16-h slice; lane = 1 row (64 rows/blk).
//   Hot loop: SMEM scalar operands + packed v_pk_fma_f32 + rcp-pair trick
//   (1 trans per 2 elements). Zero LDS / zero VMEM in the loop.
//   Grid 1024 = 4 blocks/CU = 32 waves/CU (needs VGPR <= 64).
// ---------------------------------------------------------------------------
__global__ __launch_bounds__(512, 8) void main_kernel(
    const float* __restrict__ x, const float* __restrict__ WTc,
    const float* __restrict__ ekT, const float* __restrict__ w2n,
    float* __restrict__ out) {
  __shared__ float pSum[8][64][18];          // 36.9 KB; stride 18 -> b64 ok
  int t = threadIdx.x;
  int lane = t & 63;
  int wv = __builtin_amdgcn_readfirstlane(t >> 6);   // wave id: 0..7
  int row0 = blockIdx.x * 64;
  int sb = row0 >> 11;
  int r = row0 + lane;

  // ---- private x row -> 16 packed v2f (32 VGPRs) ----
  v2f xr[16];
  {
    const float4* xp = (const float4*)(x + (size_t)r * 32);
#pragma unroll
    for (int i = 0; i < 8; ++i) {
      float4 v = xp[i];
      xr[2 * i]     = (v2f){v.x, v.y};
      xr[2 * i + 1] = (v2f){v.z, v.w};
    }
  }

  // wave-uniform scalar-pipe bases (16-h slice per wave)
  c4f* Wb  = as_const(WTc + wv * 16 * 32);
  c4f* ekb = as_const(ekT + (size_t)sb * 2048 + wv * 16 * 16);
  c4f* w2b = as_const(w2n + wv * 16);

  v2f acc[8];
#pragma unroll
  for (int j = 0; j < 8; ++j) acc[j] = (v2f){0.f, 0.f};

#pragma unroll 1
  for (int hh = 0; hh < 16; ++hh) {
    c4f* wr = Wb + hh * 32;                  // s_load (128 B)
    v2f p = (v2f){0.f, 0.f};
#pragma unroll
    for (int i = 0; i < 16; ++i) {
      v2f w = (v2f){wr[2 * i], wr[2 * i + 1]};   // SGPR pair operand
      p = fma2(xr[i], w, p);                     // v_pk_fma_f32
    }
    float ex = EXP2F(p.x + p.y);
    c4f* ekr = ekb + hh * 16;                // s_load (64 B)
    float w2 = w2b[hh];                      // s_load (4 B)
    v2f ex2 = (v2f){ex, ex};
    v2f w22 = (v2f){w2, w2};
#pragma unroll
    for (int j = 0; j < 8; ++j) {            // 2 k per group, 1 rcp per group
      v2f ek2 = (v2f){ekr[2 * j], ekr[2 * j + 1]};
      v2f tt = fma2(ex2, ek2, (v2f){1.f, 1.f});
      float pr = tt.x * tt.y;
      float rc = RCPF(pr);
      v2f inv = (v2f){tt.y * rc, tt.x * rc}; // 1/t0, 1/t1
      acc[j] = fma2(w22, inv, acc[j]);
    }
  }

  // ---- cross-wave reduction (once) ----
#pragma unroll
  for (int j = 0; j < 8; ++j)
    *(v2f*)&pSum[wv][lane][2 * j] = acc[j];  // ds_write_b64
  __syncthreads();

  // thread t: row rr = t>>3 (0..63), k-pair kp = t&7 (k = 2kp, 2kp+1)
  int rr = t >> 3, kp = t & 7;
  v2f g = (v2f){0.f, 0.f};
#pragma unroll
  for (int w = 0; w < 8; ++w) {
    v2f v = *(const v2f*)&pSum[w][rr][2 * kp];
    g.x += v.x; g.y += v.y;
  }

  // softmax over 16 k = 2 in-thread x 8 lanes (shuffle width 8)
  float mx = fmaxf(g.x, g.y);
#pragma unroll
  for (int m = 1; m <= 4; m <<= 1) mx = fmaxf(mx, __shfl_xor(mx, m, 8));
  float p0 = EXP2F((g.x - mx) * L2E), p1 = EXP2F((g.y - mx) * L2E);
  float sum = p0 + p1;
#pragma unroll
  for (int m = 1; m <= 4; m <<= 1) sum += __shfl_xor(sum, m, 8);
  float inv = RCPF(sum);
  *(float2*)&out[(size_t)(row0 + rr) * 16 + 2 * kp] = make_float2(p0 * inv, p1 * inv);
}

// ---------------------------------------------------------------------------
extern "C" void kernel_launch(void* const* d_in, const int* in_sizes, int n_in,
                              void* d_out, int out_size, void* d_ws, size_t ws_size,
                              hipStream_t stream) {
  const float* x   = (const float*)d_in[0];
  const float* mu  = (const float*)d_in[1];
  const float* tau = (const float*)d_in[2];
  const float* W1  = (const float*)d_in[3];
  const float* b1  = (const float*)d_in[4];
  const float* W2  = (const float*)d_in[5];
  // b2 (d_in[6]) and sum(W2) are k-uniform -> cancelled by softmax.
  float* out = (float*)d_out;

  float* ekT = (float*)d_ws;              // 32*2048 f32 = 256 KB
  float* WTc = ekT + 32 * 2048;           // 4096 f32 = 16 KB
  float* w2n = WTc + 4096;                // 128 f32
  (void)in_sizes; (void)n_in; (void)out_size; (void)ws_size;

  prep_kernel<<<256, 256, 0, stream>>>(mu, tau, W1, b1, W2, ekT, WTc, w2n);
  main_kernel<<<1024, 512, 0, stream>>>(x, WTc, ekT, w2n, out);
}